// Round 2
// baseline (558.484 us; speedup 1.0000x reference)
//
#include <hip/hip_runtime.h>
#include <math.h>

#define T 2048
#define B 32
#define N 1024
#define NCHUNK 32           // t-chunks for content partial sums
#define TCHUNK (T / NCHUNK) // 64 timesteps per chunk

__device__ __forceinline__ float fast_tanh(float x) {
    // 1 - 2/(e^{2x}+1): saturates at +/-1, no NaN at overflow.
    // v_rcp_f32 approx is ~1 ulp — far inside the absmax threshold.
    float e = __expf(2.0f * x);
    return 1.0f - 2.0f * __builtin_amdgcn_rcpf(e + 1.0f);
}

__device__ __forceinline__ float wave_reduce_sum(float v) {
    #pragma unroll
    for (int off = 32; off > 0; off >>= 1) v += __shfl_down(v, off, 64);
    return v;
}

// dec[b][i] = sum_j hx[b][j] * Ws_w[i][j] + Ws_b[i]
__global__ void dec_feature_kernel(const float* __restrict__ hx,
                                   const float* __restrict__ Ws_w,
                                   const float* __restrict__ Ws_b,
                                   float* __restrict__ dec) {
    int w = blockIdx.x * 4 + (threadIdx.x >> 6);
    int lane = threadIdx.x & 63;
    int i = w >> 5;
    int b = w & 31;
    const float4* wr = (const float4*)(Ws_w + (size_t)i * N);
    const float4* hr = (const float4*)(hx + (size_t)b * N);
    float acc = 0.f;
    #pragma unroll
    for (int k = 0; k < 4; ++k) {
        float4 a = wr[k * 64 + lane];
        float4 h = hr[k * 64 + lane];
        acc += a.x * h.x + a.y * h.y + a.z * h.z + a.w * h.w;
    }
    acc = wave_reduce_sum(acc);
    if (lane == 0) dec[(size_t)b * N + i] = acc + Ws_b[i];
}

// Fused scores + online-softmax + weighted partial sum (flash-style).
// Block (chunk, b): computes s_t = sum_n tanh(ef[t][b][n]+dec[b][n])*v_w[n]
// for its 64 timesteps (v_b dropped: cancels in softmax), then local stats
//   m_c = max_t s_t,  l_c = sum_t exp(s_t - m_c)            (unmasked, per ref)
//   partial[c][b][n] = sum_t exp(s_t - m_c)*mask[b][t]*eo[t][b][n]
// Final rescale happens in content_reduce_kernel.
__global__ void score_content_kernel(const float* __restrict__ ef,
                                     const float* __restrict__ eo,
                                     const float* __restrict__ dec,
                                     const float* __restrict__ v_w,
                                     const float* __restrict__ mask,
                                     float* __restrict__ partial,
                                     float* __restrict__ mstat,
                                     float* __restrict__ lstat) {
    int b = blockIdx.y;
    int chunk = blockIdx.x;
    int tid = threadIdx.x;
    int lane = tid & 63, wid = tid >> 6;
    __shared__ float s_sh[TCHUNK];   // raw scores for this chunk
    __shared__ float p_sh[TCHUNK];   // exp(s-m)*mask weights

    // dec row + v_w fragments, reused across the wave's 16 timesteps
    const float4* d4 = (const float4*)(dec + (size_t)b * N);
    const float4* v4 = (const float4*)v_w;
    float4 dreg[4], vreg[4];
    #pragma unroll
    for (int k = 0; k < 4; ++k) {
        dreg[k] = d4[k * 64 + lane];
        vreg[k] = v4[k * 64 + lane];
    }

    // Phase A: scores (each wave handles tt = wid, wid+4, ...)
    for (int tt = wid; tt < TCHUNK; tt += 4) {
        int t = chunk * TCHUNK + tt;
        const float4* e4 = (const float4*)(ef + ((size_t)t * B + b) * N);
        float acc = 0.f;
        #pragma unroll
        for (int k = 0; k < 4; ++k) {
            float4 e = e4[k * 64 + lane];
            acc += fast_tanh(e.x + dreg[k].x) * vreg[k].x
                 + fast_tanh(e.y + dreg[k].y) * vreg[k].y
                 + fast_tanh(e.z + dreg[k].z) * vreg[k].z
                 + fast_tanh(e.w + dreg[k].w) * vreg[k].w;
        }
        acc = wave_reduce_sum(acc);
        if (lane == 0) s_sh[tt] = acc;
    }
    __syncthreads();

    // local max (broadcast LDS reads, redundantly per thread — cheap)
    float m = -1e30f;
    #pragma unroll
    for (int tt = 0; tt < TCHUNK; ++tt) m = fmaxf(m, s_sh[tt]);

    // wave 0 (tid<64): weights + local exp-sum
    if (tid < TCHUNK) {
        int t = chunk * TCHUNK + tid;
        float ex = __expf(s_sh[tid] - m);
        p_sh[tid] = ex * mask[(size_t)b * T + t];
        float l = wave_reduce_sum(ex);
        if (tid == 0) {
            mstat[chunk * B + b] = m;
            lstat[chunk * B + b] = l;
        }
    }
    __syncthreads();

    // Phase B: weighted eo accumulation
    const float4* base = (const float4*)eo;
    float4 acc = {0.f, 0.f, 0.f, 0.f};
    #pragma unroll 4
    for (int tt = 0; tt < TCHUNK; ++tt) {
        int t = chunk * TCHUNK + tt;
        float a = p_sh[tt];
        float4 e = base[((size_t)t * B + b) * (N / 4) + tid];
        acc.x += a * e.x; acc.y += a * e.y; acc.z += a * e.z; acc.w += a * e.w;
    }
    ((float4*)partial)[((size_t)chunk * B + b) * (N / 4) + tid] = acc;
}

// content[b][n] = (sum_c e^{m_c-M} partial[c][b][n]) / (sum_c e^{m_c-M} l_c)
__global__ void content_reduce_kernel(const float* __restrict__ partial,
                                      const float* __restrict__ mstat,
                                      const float* __restrict__ lstat,
                                      float* __restrict__ content) {
    int g = blockIdx.x * 256 + threadIdx.x;  // 0 .. B*N/4-1 (float4 units)
    int b = g >> 8;                          // N/4 = 256
    float M = -1e30f;
    #pragma unroll
    for (int c = 0; c < NCHUNK; ++c) M = fmaxf(M, mstat[c * B + b]);
    float w[NCHUNK];
    float L = 0.f;
    #pragma unroll
    for (int c = 0; c < NCHUNK; ++c) {
        w[c] = __expf(mstat[c * B + b] - M);
        L += w[c] * lstat[c * B + b];
    }
    float invL = __builtin_amdgcn_rcpf(L);
    const float4* p4 = (const float4*)partial;
    float4 acc = {0.f, 0.f, 0.f, 0.f};
    #pragma unroll 8
    for (int c = 0; c < NCHUNK; ++c) {
        float4 v = p4[(size_t)c * (B * N / 4) + g];
        acc.x += w[c] * v.x; acc.y += w[c] * v.y;
        acc.z += w[c] * v.z; acc.w += w[c] * v.w;
    }
    acc.x *= invL; acc.y *= invL; acc.z *= invL; acc.w *= invL;
    ((float4*)content)[g] = acc;
}

// out[b][i] = tanh( dot(content[b], lin_w[i][:N]) + dot(hx[b], lin_w[i][N:]) + lin_b[i] )
__global__ void out_kernel(const float* __restrict__ content,
                           const float* __restrict__ hx,
                           const float* __restrict__ lin_w,
                           const float* __restrict__ lin_b,
                           float* __restrict__ out) {
    int w = blockIdx.x * 4 + (threadIdx.x >> 6);
    int lane = threadIdx.x & 63;
    int i = w >> 5;
    int b = w & 31;
    const float4* wr = (const float4*)(lin_w + (size_t)i * 2 * N);
    const float4* cr = (const float4*)(content + (size_t)b * N);
    const float4* hr = (const float4*)(hx + (size_t)b * N);
    float acc = 0.f;
    #pragma unroll
    for (int k = 0; k < 4; ++k) {
        float4 a = wr[k * 64 + lane];
        float4 c = cr[k * 64 + lane];
        acc += a.x * c.x + a.y * c.y + a.z * c.z + a.w * c.w;
    }
    #pragma unroll
    for (int k = 0; k < 4; ++k) {
        float4 a = wr[256 + k * 64 + lane];
        float4 h = hr[k * 64 + lane];
        acc += a.x * h.x + a.y * h.y + a.z * h.z + a.w * h.w;
    }
    acc = wave_reduce_sum(acc);
    if (lane == 0) out[(size_t)b * N + i] = fast_tanh(acc + lin_b[i]);
}

extern "C" void kernel_launch(void* const* d_in, const int* in_sizes, int n_in,
                              void* d_out, int out_size, void* d_ws, size_t ws_size,
                              hipStream_t stream) {
    const float* hx    = (const float*)d_in[0];
    const float* eo    = (const float*)d_in[1];
    const float* ef    = (const float*)d_in[2];
    const float* mask  = (const float*)d_in[3];
    const float* Ws_w  = (const float*)d_in[4];
    const float* Ws_b  = (const float*)d_in[5];
    const float* v_w   = (const float*)d_in[6];
    /* v_b cancels in softmax */
    const float* lin_w = (const float*)d_in[8];
    const float* lin_b = (const float*)d_in[9];
    float* out = (float*)d_out;

    float* ws      = (float*)d_ws;
    float* dec     = ws;                      // B*N        = 32768 floats
    float* mstat   = dec + B * N;             // NCHUNK*B   = 1024
    float* lstat   = mstat + NCHUNK * B;      // NCHUNK*B   = 1024
    float* content = lstat + NCHUNK * B;      // B*N        = 32768
    float* partial = content + B * N;         // NCHUNK*B*N = 1048576 floats (4 MB)

    dec_feature_kernel<<<(B * N) / 4, 256, 0, stream>>>(hx, Ws_w, Ws_b, dec);
    score_content_kernel<<<dim3(NCHUNK, B), 256, 0, stream>>>(
        ef, eo, dec, v_w, mask, partial, mstat, lstat);
    content_reduce_kernel<<<(B * N / 4) / 256, 256, 0, stream>>>(
        partial, mstat, lstat, content);
    out_kernel<<<(B * N) / 4, 256, 0, stream>>>(content, hx, lin_w, lin_b, out);
}